// Round 2
// baseline (1010.695 us; speedup 1.0000x reference)
//
#include <hip/hip_runtime.h>
#include <stdint.h>

#define NPROPS 32
#define MTOT 36      // sum over l of (2l+1), l = 0..5
#define NSAMP 2000   // N_SAMPLES (fixed by reference)
#define NGRAD 10000  // N_GRAD   (fixed by reference)

struct Ptrs6 { const float* p[6]; };

typedef float f32x4 __attribute__((ext_vector_type(4)));

__device__ __constant__ float c_factor[6] = {
  1.0f,
  0.5773502691896258f,   // 1/sqrt(3)
  0.4472135954999579f,   // 1/sqrt(5)
  0.3779644730092272f,   // 1/sqrt(7)
  0.3333333333333333f,   // 1/sqrt(9)
  0.3015113445777636f }; // 1/sqrt(11)

// ---------------------------------------------------------------------------
// datafull: out[i, l*1024 + a*32 + b] = f_l * sum_m v_l[i,m,a]*v_l[i,m,b]
// one block per sample i; thread t covers ab = 4t..4t+3 for every l.
// Output is write-once streaming -> nontemporal stores (don't pollute L2).
// ---------------------------------------------------------------------------
__global__ __launch_bounds__(256) void ps_values_kernel(
    Ptrs6 vp, float* __restrict__ out)
{
  __shared__ __align__(16) float vs[MTOT * NPROPS];  // 1152 floats, 4.6 KB
  const int i = blockIdx.x;
  const int tid = threadIdx.x;

#pragma unroll
  for (int l = 0; l < 6; ++l) {
    const int N = (2 * l + 1) * NPROPS;
    const float* src = vp.p[l] + (size_t)i * N;
    float* dst = vs + l * l * NPROPS;
    for (int t = tid; t < (N >> 2); t += 256)
      *(float4*)(dst + 4 * t) = *(const float4*)(src + 4 * t);
  }
  __syncthreads();

  const int ab0 = tid << 2;       // 0..1020 step 4
  const int a  = ab0 >> 5;        // 0..31
  const int b0 = ab0 & 31;        // 0,4,...,28
  const size_t obase = (size_t)i * 6144 + ab0;

#pragma unroll
  for (int l = 0; l < 6; ++l) {
    const int K = 2 * l + 1;
    const float* rowb = vs + l * l * NPROPS;
    float4 acc = make_float4(0.f, 0.f, 0.f, 0.f);
    for (int m = 0; m < K; ++m) {
      const float* row = rowb + m * NPROPS;
      float va = row[a];
      float4 vb = *(const float4*)(row + b0);
      acc.x += va * vb.x; acc.y += va * vb.y;
      acc.z += va * vb.z; acc.w += va * vb.w;
    }
    const float f = c_factor[l];
    f32x4 pk = { acc.x * f, acc.y * f, acc.z * f, acc.w * f };
    __builtin_nontemporal_store(pk, (f32x4*)(out + obase + l * 1024));
  }
}

// ---------------------------------------------------------------------------
// datafull_grad: out[i, x, l*1024 + a*32 + b] =
//   f_l * sum_m ( g_l[i,x,m,a]*v_l[j,m,b] + v_l[j,m,a]*g_l[i,x,m,b] ),  j=idx[i]
// one block per grad sample i; 18 slices (x,l); 6 waves (384 thr) -> exactly
// 3 passes, no idle-wave tail (was 4 waves -> 4+4+4+4+2).
// Each lane owns a 4x4 (a,b) register tile. Streaming output -> nt stores.
// ---------------------------------------------------------------------------
__global__ __launch_bounds__(384) void ps_grads_kernel(
    Ptrs6 vp, Ptrs6 gp, const int* __restrict__ gidx,
    float* __restrict__ out)
{
  __shared__ __align__(16) float vs[MTOT * NPROPS];       // 4.6 KB
  __shared__ __align__(16) float gs[3 * MTOT * NPROPS];   // 13.8 KB
  const int i = blockIdx.x;
  const int tid = threadIdx.x;
  // Clamp: a transiently-invalid index (e.g. observed mid-restore) must never
  // generate a wild gather address / VM fault; final launch has valid gidx.
  int j = gidx[i];
  j = (j < 0) ? 0 : (j >= NSAMP ? NSAMP - 1 : j);

  // stage gathered values v[j]
#pragma unroll
  for (int l = 0; l < 6; ++l) {
    const int N = (2 * l + 1) * NPROPS;
    const float* src = vp.p[l] + (size_t)j * N;
    float* dst = vs + l * l * NPROPS;
    for (int t = tid; t < (N >> 2); t += 384)
      *(float4*)(dst + 4 * t) = *(const float4*)(src + 4 * t);
  }
  // stage grads g[i]  (LDS layout: gs[x][l*l + m][p])
#pragma unroll
  for (int l = 0; l < 6; ++l) {
    const int NX = (2 * l + 1) * NPROPS;   // per-x chunk (compile-time per l)
    const float* src = gp.p[l] + (size_t)i * 3 * NX;
    for (int t = tid; t < ((3 * NX) >> 2); t += 384) {
      int e = t << 2;
      int x = e / NX;                      // div by constant -> mul/shift
      int rem = e - x * NX;
      *(float4*)(gs + x * (MTOT * NPROPS) + l * l * NPROPS + rem) =
          *(const float4*)(src + e);
    }
  }
  __syncthreads();

  const int s  = tid >> 6;            // wave id = slice-within-pass (wave-uniform)
  const int t6 = tid & 63;
  const int a0 = (t6 >> 3) << 2;      // 0,4,...,28
  const int b0 = (t6 & 7) << 2;       // 0,4,...,28
  const size_t obase = (size_t)i * 18432;

#pragma unroll
  for (int pass = 0; pass < 3; ++pass) {
    const int si = pass * 6 + s;      // 0..17, each slice exactly once
    const int x = si / 6;
    const int l = si - x * 6;
    const int K = 2 * l + 1;
    const float* vrow = vs + l * l * NPROPS;
    const float* grow = gs + x * (MTOT * NPROPS) + l * l * NPROPS;

    float acc[4][4];
#pragma unroll
    for (int r = 0; r < 4; ++r)
#pragma unroll
      for (int c = 0; c < 4; ++c) acc[r][c] = 0.f;

    for (int m = 0; m < K; ++m) {
      const float* vr = vrow + m * NPROPS;
      const float* gr = grow + m * NPROPS;
      float4 va = *(const float4*)(vr + a0);
      float4 vb = *(const float4*)(vr + b0);
      float4 ga = *(const float4*)(gr + a0);
      float4 gb = *(const float4*)(gr + b0);
      const float vaa[4] = {va.x, va.y, va.z, va.w};
      const float gaa[4] = {ga.x, ga.y, ga.z, ga.w};
      const float vbb[4] = {vb.x, vb.y, vb.z, vb.w};
      const float gbb[4] = {gb.x, gb.y, gb.z, gb.w};
#pragma unroll
      for (int r = 0; r < 4; ++r)
#pragma unroll
        for (int c = 0; c < 4; ++c)
          acc[r][c] += gaa[r] * vbb[c] + vaa[r] * gbb[c];
    }

    const float f = c_factor[l];
    float* op = out + obase + (size_t)x * 6144 + l * 1024 + b0;
#pragma unroll
    for (int r = 0; r < 4; ++r) {
      f32x4 pk = { acc[r][0] * f, acc[r][1] * f,
                   acc[r][2] * f, acc[r][3] * f };
      __builtin_nontemporal_store(pk, (f32x4*)(op + (a0 + r) * 32));
    }
  }
}

extern "C" void kernel_launch(void* const* d_in, const int* in_sizes, int n_in,
                              void* d_out, int out_size, void* d_ws, size_t ws_size,
                              hipStream_t stream)
{
  (void)in_sizes; (void)n_in; (void)out_size; (void)d_ws; (void)ws_size;
  // Input order is the setup_inputs() dict order (interleaved, verified by
  // round-2 pre-timing pass): values_0, grads_0, values_1, grads_1, ...,
  // values_5, grads_5, grad_sample_idx. All shapes are compile-time constants;
  // no dependence on transient host state.
  Ptrs6 vp, gp;
  for (int l = 0; l < 6; ++l) {
    vp.p[l] = (const float*)d_in[2 * l];
    gp.p[l] = (const float*)d_in[2 * l + 1];
  }
  const int* gidx = (const int*)d_in[12];
  float* out = (float*)d_out;

  ps_values_kernel<<<NSAMP, 256, 0, stream>>>(vp, out);
  ps_grads_kernel<<<NGRAD, 384, 0, stream>>>(
      vp, gp, gidx, out + (size_t)NSAMP * 6144);
}

// Round 3
// 908.492 us; speedup vs baseline: 1.1125x; 1.1125x over previous
//
#include <hip/hip_runtime.h>
#include <stdint.h>

#define NPROPS 32
#define MTOT 36      // sum over l of (2l+1), l = 0..5
#define NSAMP 2000   // N_SAMPLES (fixed by reference)
#define NGRAD 10000  // N_GRAD   (fixed by reference)

struct Ptrs6 { const float* p[6]; };

typedef float f32x4 __attribute__((ext_vector_type(4)));

__device__ __constant__ float c_factor[6] = {
  1.0f,
  0.5773502691896258f,   // 1/sqrt(3)
  0.4472135954999579f,   // 1/sqrt(5)
  0.3779644730092272f,   // 1/sqrt(7)
  0.3333333333333333f,   // 1/sqrt(9)
  0.3015113445777636f }; // 1/sqrt(11)

// Balanced slice schedule for the grads kernel: 18 slices (x,l), K = 2l+1.
// Wave w executes c_wslice[w][0..c_wcount[w]-1]; slice id = x*6 + l.
// Per-wave sum of K: 27 / 27 / 26 / 28 (parity-optimal; round-0's 384-thread
// layout pinned each wave to one l -> 11x imbalance -> 19% regression).
// Longest slices first so the tail is short work.
__device__ __constant__ unsigned char c_wslice[4][5] = {
  { 0*6+5, 0*6+3, 0*6+2, 0*6+1, 0*6+0 },   // K: 11,7,5,3,1 = 27
  { 1*6+5, 1*6+3, 1*6+2, 1*6+1, 1*6+0 },   // K: 11,7,5,3,1 = 27
  { 0*6+4, 1*6+4, 2*6+3, 2*6+0, 255   },   // K: 9,9,7,1   = 26
  { 2*6+5, 2*6+4, 2*6+2, 2*6+1, 255   },   // K: 11,9,5,3  = 28
};
__device__ __constant__ unsigned char c_wcount[4] = { 5, 5, 4, 4 };

// ---------------------------------------------------------------------------
// datafull: out[i, l*1024 + a*32 + b] = f_l * sum_m v_l[i,m,a]*v_l[i,m,b]
// one block per sample i; thread t covers ab = 4t..4t+3 for every l.
// Output is write-once streaming -> nontemporal stores.
// ---------------------------------------------------------------------------
__global__ __launch_bounds__(256) void ps_values_kernel(
    Ptrs6 vp, float* __restrict__ out)
{
  __shared__ __align__(16) float vs[MTOT * NPROPS];  // 1152 floats, 4.6 KB
  const int i = blockIdx.x;
  const int tid = threadIdx.x;

#pragma unroll
  for (int l = 0; l < 6; ++l) {
    const int N = (2 * l + 1) * NPROPS;
    const float* src = vp.p[l] + (size_t)i * N;
    float* dst = vs + l * l * NPROPS;
    for (int t = tid; t < (N >> 2); t += 256)
      *(float4*)(dst + 4 * t) = *(const float4*)(src + 4 * t);
  }
  __syncthreads();

  const int ab0 = tid << 2;       // 0..1020 step 4
  const int a  = ab0 >> 5;        // 0..31
  const int b0 = ab0 & 31;        // 0,4,...,28
  const size_t obase = (size_t)i * 6144 + ab0;

#pragma unroll
  for (int l = 0; l < 6; ++l) {
    const int K = 2 * l + 1;
    const float* rowb = vs + l * l * NPROPS;
    float4 acc = make_float4(0.f, 0.f, 0.f, 0.f);
    for (int m = 0; m < K; ++m) {
      const float* row = rowb + m * NPROPS;
      float va = row[a];
      float4 vb = *(const float4*)(row + b0);
      acc.x += va * vb.x; acc.y += va * vb.y;
      acc.z += va * vb.z; acc.w += va * vb.w;
    }
    const float f = c_factor[l];
    f32x4 pk = { acc.x * f, acc.y * f, acc.z * f, acc.w * f };
    __builtin_nontemporal_store(pk, (f32x4*)(out + obase + l * 1024));
  }
}

// ---------------------------------------------------------------------------
// datafull_grad: out[i, x, l*1024 + a*32 + b] =
//   f_l * sum_m ( g_l[i,x,m,a]*v_l[j,m,b] + v_l[j,m,a]*g_l[i,x,m,b] ),  j=idx[i]
// one block (256 thr = 4 waves) per grad sample i; 18 (x,l) slices assigned
// per the balanced c_wslice table. Each lane owns a 4x4 (a,b) register tile.
// 8 blocks/CU (full 32 waves/CU). Streaming output -> nt stores.
// ---------------------------------------------------------------------------
__global__ __launch_bounds__(256) void ps_grads_kernel(
    Ptrs6 vp, Ptrs6 gp, const int* __restrict__ gidx,
    float* __restrict__ out)
{
  __shared__ __align__(16) float vs[MTOT * NPROPS];       // 4.6 KB
  __shared__ __align__(16) float gs[3 * MTOT * NPROPS];   // 13.8 KB
  const int i = blockIdx.x;
  const int tid = threadIdx.x;
  // Clamp: a transiently-invalid index (e.g. observed mid-restore) must never
  // generate a wild gather address / VM fault; final launch has valid gidx.
  int j = gidx[i];
  j = (j < 0) ? 0 : (j >= NSAMP ? NSAMP - 1 : j);

  // stage gathered values v[j]
#pragma unroll
  for (int l = 0; l < 6; ++l) {
    const int N = (2 * l + 1) * NPROPS;
    const float* src = vp.p[l] + (size_t)j * N;
    float* dst = vs + l * l * NPROPS;
    for (int t = tid; t < (N >> 2); t += 256)
      *(float4*)(dst + 4 * t) = *(const float4*)(src + 4 * t);
  }
  // stage grads g[i]  (LDS layout: gs[x][l*l + m][p])
#pragma unroll
  for (int l = 0; l < 6; ++l) {
    const int NX = (2 * l + 1) * NPROPS;   // per-x chunk (compile-time per l)
    const float* src = gp.p[l] + (size_t)i * 3 * NX;
    for (int t = tid; t < ((3 * NX) >> 2); t += 256) {
      int e = t << 2;
      int x = e / NX;                      // div by constant -> mul/shift
      int rem = e - x * NX;
      *(float4*)(gs + x * (MTOT * NPROPS) + l * l * NPROPS + rem) =
          *(const float4*)(src + e);
    }
  }
  __syncthreads();

  const int s  = tid >> 6;            // wave id (wave-uniform)
  const int t6 = tid & 63;
  const int a0 = (t6 >> 3) << 2;      // 0,4,...,28
  const int b0 = (t6 & 7) << 2;       // 0,4,...,28
  const size_t obase = (size_t)i * 18432;
  const int nsl = c_wcount[s];

  for (int k = 0; k < nsl; ++k) {
    const int si = c_wslice[s][k];    // wave-uniform scalar load
    const int x = si / 6;
    const int l = si - x * 6;
    const int K = 2 * l + 1;
    const float* vrow = vs + l * l * NPROPS;
    const float* grow = gs + x * (MTOT * NPROPS) + l * l * NPROPS;

    float acc[4][4];
#pragma unroll
    for (int r = 0; r < 4; ++r)
#pragma unroll
      for (int c = 0; c < 4; ++c) acc[r][c] = 0.f;

    for (int m = 0; m < K; ++m) {
      const float* vr = vrow + m * NPROPS;
      const float* gr = grow + m * NPROPS;
      float4 va = *(const float4*)(vr + a0);
      float4 vb = *(const float4*)(vr + b0);
      float4 ga = *(const float4*)(gr + a0);
      float4 gb = *(const float4*)(gr + b0);
      const float vaa[4] = {va.x, va.y, va.z, va.w};
      const float gaa[4] = {ga.x, ga.y, ga.z, ga.w};
      const float vbb[4] = {vb.x, vb.y, vb.z, vb.w};
      const float gbb[4] = {gb.x, gb.y, gb.z, gb.w};
#pragma unroll
      for (int r = 0; r < 4; ++r)
#pragma unroll
        for (int c = 0; c < 4; ++c)
          acc[r][c] += gaa[r] * vbb[c] + vaa[r] * gbb[c];
    }

    const float f = c_factor[l];
    float* op = out + obase + (size_t)x * 6144 + l * 1024 + b0;
#pragma unroll
    for (int r = 0; r < 4; ++r) {
      f32x4 pk = { acc[r][0] * f, acc[r][1] * f,
                   acc[r][2] * f, acc[r][3] * f };
      __builtin_nontemporal_store(pk, (f32x4*)(op + (a0 + r) * 32));
    }
  }
}

extern "C" void kernel_launch(void* const* d_in, const int* in_sizes, int n_in,
                              void* d_out, int out_size, void* d_ws, size_t ws_size,
                              hipStream_t stream)
{
  (void)in_sizes; (void)n_in; (void)out_size; (void)d_ws; (void)ws_size;
  // Input order is the setup_inputs() dict order (interleaved): values_0,
  // grads_0, values_1, grads_1, ..., values_5, grads_5, grad_sample_idx.
  Ptrs6 vp, gp;
  for (int l = 0; l < 6; ++l) {
    vp.p[l] = (const float*)d_in[2 * l];
    gp.p[l] = (const float*)d_in[2 * l + 1];
  }
  const int* gidx = (const int*)d_in[12];
  float* out = (float*)d_out;

  ps_values_kernel<<<NSAMP, 256, 0, stream>>>(vp, out);
  ps_grads_kernel<<<NGRAD, 256, 0, stream>>>(
      vp, gp, gidx, out + (size_t)NSAMP * 6144);
}